// Round 3
// baseline (3763.071 us; speedup 1.0000x reference)
//
#include <hip/hip_runtime.h>

// QINCo round 13: occupancy attack. k_step LDS 64KB -> 32KB by processing the
// 64-row tile as TWO serial 32-row subtiles (Z/H hold 32 rows each). 5 blocks/CU
// by LDS (was 2) -> 2-2.5x waves/SIMD to feed the MFMA pipe. All fragment /
// rotation / epilogue math identical to R12 with the second m-tile removed.
// Best-of-two-subtiles carried in registers + conditional BESTZ overwrite, so
// the ws layout is unchanged. Weight A-frags are re-loaded per subtile
// (L2-resident; 2x L2 traffic, still <2/3 of L2 ceiling).
// Shapes: D=128, M=8, K=256, L=2, H=256, BS=1024.
// Out layout (floats): xhat[1024*128] | codes[1024*8] | side[8][1024*128]

typedef _Float16 f16;
typedef f16 half4_t __attribute__((ext_vector_type(4)));
typedef f16 half8_t __attribute__((ext_vector_type(8)));
typedef float f32x16 __attribute__((ext_vector_type(16)));

#define OUT_CODES 131072
#define OUT_SIDE  139264

// ws float offsets (unchanged from R12)
#define WS_XHAT  0          // [1024][128]
#define WS_RB    131072     // [1024][128]  r = x - xhat
#define WS_Y     262144     // [1024][128]  y = xhat @ Wx^T
#define WS_ZC    393216     // [256][128]   zc = cb + cb@Wz^T + bc
#define WS_BESTD 425984     // [1024][4]
#define WS_BESTI 430080     // [1024][4] (int)
#define WS_BESTZ 434176     // [1024][4][128]
#define WS_WSPLIT 960000    // f16 region: W1H|W1L|W2H|W2L, NW1 halfs each
#define NW1 458752          // 7*2*256*128

#define HLO 4096            // hi->lo LDS offset (halfs), compile-time (32-row tiles)

__device__ __forceinline__ f32x16 mfma_f16(half8_t a, half8_t b, f32x16 c) {
  return __builtin_amdgcn_mfma_f32_32x32x16_f16(a, b, c, 0, 0, 0);
}

// ---------------- weight pre-split: fp32 -> scaled (x256) fp16 hi/lo ----------------
__global__ __launch_bounds__(256) void k_wsplit(const float* __restrict__ W1,
    const float* __restrict__ W2, f16* __restrict__ wsh)
{
  int i = (blockIdx.x * 256 + threadIdx.x) * 4;      // [0, 2*NW1)
  const float* src;
  f16* hi;
  if (i < NW1) { src = W1 + i; hi = wsh + i; }
  else         { src = W2 + (i - NW1); hi = wsh + 2 * NW1 + (i - NW1); }
  f16* lo = hi + NW1;
  float4 v = *(const float4*)src;
  half4_t h, l;
  float s;
  s = v.x * 256.f; h[0] = (f16)s; l[0] = (f16)(s - (float)h[0]);
  s = v.y * 256.f; h[1] = (f16)s; l[1] = (f16)(s - (float)h[1]);
  s = v.z * 256.f; h[2] = (f16)s; l[2] = (f16)(s - (float)h[2]);
  s = v.w * 256.f; h[3] = (f16)s; l[3] = (f16)(s - (float)h[3]);
  *(half4_t*)hi = h;
  *(half4_t*)lo = l;
}

// ---------------- step 0: nearest codebook0 row ----------------
__global__ __launch_bounds__(256) void k_step0(const float* __restrict__ x,
    const float* __restrict__ cb0, float* __restrict__ ws, float* __restrict__ out)
{
  __shared__ float xs[128];
  __shared__ float redv[4];
  __shared__ int   redi[4];
  __shared__ int   kwin;
  int tx = threadIdx.x, b = blockIdx.x;
  if (tx < 128) xs[tx] = x[b * 128 + tx];
  __syncthreads();
  const float* c = cb0 + tx * 128;   // k = tx
  float s = 0.f;
  for (int d = 0; d < 128; d += 4) {
    float4 cv = *(const float4*)(c + d);
    float4 xv = *(const float4*)(xs + d);
    float a0 = xv.x - cv.x, a1 = xv.y - cv.y, a2 = xv.z - cv.z, a3 = xv.w - cv.w;
    s += a0 * a0 + a1 * a1 + a2 * a2 + a3 * a3;
  }
  float v = s; int idx = tx;
  for (int off = 32; off; off >>= 1) {
    float v2 = __shfl_xor(v, off);
    int   i2 = __shfl_xor(idx, off);
    if (v2 < v || (v2 == v && i2 < idx)) { v = v2; idx = i2; }
  }
  if ((tx & 63) == 0) { redv[tx >> 6] = v; redi[tx >> 6] = idx; }
  __syncthreads();
  if (tx == 0) {
    float bv = redv[0]; int bi = redi[0];
    for (int w = 1; w < 4; w++)
      if (redv[w] < bv || (redv[w] == bv && redi[w] < bi)) { bv = redv[w]; bi = redi[w]; }
    kwin = bi;
    out[OUT_CODES + b * 8] = (float)bi;
  }
  __syncthreads();
  int k = kwin;
  if (tx < 128) {
    float xh = cb0[k * 128 + tx];
    ws[WS_XHAT + b * 128 + tx] = xh;
    ws[WS_RB   + b * 128 + tx] = xs[tx] - xh;
    out[OUT_SIDE + b * 128 + tx] = xh;   // side[0]
  }
}

// ---------------- per-step prep: zc and y (fp32) ----------------
__global__ __launch_bounds__(128) void k_prep(const float* __restrict__ cb,
    const float* __restrict__ Wc, const float* __restrict__ bcm, float* __restrict__ ws)
{
  __shared__ float row[128];
  int tx = threadIdx.x, blk = blockIdx.x;
  if (blk < 256) {          // zc[k][i] = cb[k][i] + sum_d cb[k][d]*Wc[i][d] + bc[i]
    row[tx] = cb[blk * 128 + tx];
    __syncthreads();
    const float* wrow = Wc + tx * 256;
    float s = 0.f;
    for (int d = 0; d < 128; d += 4) {
      float4 wv = *(const float4*)(wrow + d);
      float4 zv = *(const float4*)(row + d);
      s += wv.x * zv.x + wv.y * zv.y + wv.z * zv.z + wv.w * zv.w;
    }
    ws[WS_ZC + blk * 128 + tx] = row[tx] + s + bcm[tx];
  } else {                  // y[b][i] = sum_d xhat[b][d]*Wc[i][128+d]
    int b = blk - 256;
    row[tx] = ws[WS_XHAT + b * 128 + tx];
    __syncthreads();
    const float* wrow = Wc + tx * 256 + 128;
    float s = 0.f;
    for (int d = 0; d < 128; d += 4) {
      float4 wv = *(const float4*)(wrow + d);
      float4 zv = *(const float4*)(row + d);
      s += wv.x * zv.x + wv.y * zv.y + wv.z * zv.z + wv.w * zv.w;
    }
    ws[WS_Y + b * 128 + tx] = s;
  }
}

// ---------------- main step kernel ----------------
// 256 threads = 4 waves. lane: col = lane&31, koct = lane>>5.
// Two serial 32-row subtiles per block; LDS rows 128 halfs, 32 rows each of
// Zh/Zl/Hh/Hl (32KB total). Logical d of row m at phys (d + 8*(m&15)) & 127.
// Per subtile, per layer (R12 ladder minus the second m-tile):
//   G1(hf0) | storeH0 | bar | G2(hf0) | loadA1(hf1) | G1(hf1) | bar |
//   storeH1 | bar | G2(hf1) | epi2 | bar
// C/D layout: col(lane&31) = N index (m); row = (reg&3)+8*(reg>>2)+4*koct.
__global__ __launch_bounds__(256, 4) void k_step(const f16* __restrict__ wsh,
    float* __restrict__ ws, int sm)
{
  __shared__ __align__(16) f16 lds[16384];     // 32 KB exactly
  f16* Zh = lds;            // [32][128]
  f16* Zl = lds + HLO;
  f16* Hh = lds + 2 * HLO;
  f16* Hl = lds + 3 * HLO;  // Hl - Hh == Zl - Zh == HLO by construction
  int tx = threadIdx.x;
  int lane = tx & 63, w = tx >> 6;
  int col = lane & 31, koct = lane >> 5;
  int b = blockIdx.x >> 2, t = blockIdx.x & 3, k0 = t << 6;

  const int rot0 = (col & 15) << 3;        // rotation for row col
  const f16* Zr0 = Zh + (col << 7);
  const f16* Hr0 = Hh + (col << 7);
  float* pd = (float*)Hh;                  // dist scratch (H dead by then)
  int* rwin = (int*)Hh + 64;

  float bestd = 3.4e38f;                   // meaningful in tx==0 only
  int   besti = 0;

  for (int st = 0; st < 2; st++) {
    int kb = k0 + (st << 5);

    // ---- init Z = zc[kb+m] + y[b], split x256 into Zh/Zl (rotated store) ----
    {
      const float* zc = ws + WS_ZC + kb * 128;
      const float* y  = ws + WS_Y + b * 128;
      for (int idx = tx; idx < 512; idx += 256) {
        int m = idx & 31, d0 = (idx >> 5) << 3;
        float4 a  = *(const float4*)(zc + m * 128 + d0);
        float4 bb = *(const float4*)(zc + m * 128 + d0 + 4);
        float4 ya = *(const float4*)(y + d0);
        float4 yb = *(const float4*)(y + d0 + 4);
        float sv[8] = {a.x + ya.x, a.y + ya.y, a.z + ya.z, a.w + ya.w,
                       bb.x + yb.x, bb.y + yb.y, bb.z + yb.z, bb.w + yb.w};
        half8_t h8, l8;
#pragma unroll
        for (int j = 0; j < 8; j++) {
          float v = sv[j] * 256.f;
          f16 h = (f16)v; h8[j] = h; l8[j] = (f16)(v - (float)h);
        }
        int c0 = (d0 + ((m & 15) << 3)) & 127;
        *(half8_t*)(Zh + (m << 7) + c0) = h8;
        *(half8_t*)(Zl + (m << 7) + c0) = l8;
      }
    }
    __syncthreads();

    for (int l = 0; l < 2; l++) {
      const f16* w1h = wsh + (size_t)((sm * 2 + l) * 256) * 128;
      const f16* w2h = wsh + 2 * NW1 + (size_t)((sm * 2 + l) * 128) * 256;
      f32x16 acc2;
#pragma unroll
      for (int i = 0; i < 16; i++) acc2[i] = 0.f;

      // ================= hf 0 =================
      half8_t a1hv[8], a1lv[8];
      {
        const f16* a1p = w1h + (size_t)((w << 5) + col) * 128 + (koct << 3);
#pragma unroll
        for (int kc = 0; kc < 8; kc++) {
          a1hv[kc] = *(const half8_t*)(a1p + (kc << 4));
          a1lv[kc] = *(const half8_t*)(a1p + NW1 + (kc << 4));
        }
      }
      f32x16 acc1;
#pragma unroll
      for (int i = 0; i < 16; i++) acc1[i] = 0.f;
      __builtin_amdgcn_s_setprio(1);
#pragma unroll
      for (int kc = 0; kc < 8; kc++) {
        int poff = (((kc << 4) + (koct << 3)) + rot0) & 127;
        half8_t bh0 = *(const half8_t*)(Zr0 + poff);
        half8_t bl0 = *(const half8_t*)(Zr0 + HLO + poff);
        acc1 = mfma_f16(a1hv[kc], bh0, acc1);
        acc1 = mfma_f16(a1lv[kc], bh0, acc1);
        acc1 = mfma_f16(a1hv[kc], bl0, acc1);
      }
      __builtin_amdgcn_s_setprio(0);

      // a2(hf0) loads: hide under epilogue + barrier
      half8_t a2hv[8], a2lv[8];
      {
        const f16* a2p = w2h + (size_t)((w << 5) + col) * 256 + (koct << 3);
#pragma unroll
        for (int kc = 0; kc < 8; kc++) {
          a2hv[kc] = *(const half8_t*)(a2p + (kc << 4));
          a2lv[kc] = *(const half8_t*)(a2p + NW1 + (kc << 4));
        }
      }

      // epilogue1: relu, rescale (x 2^-8), split, store H(hf0) at row m=col
#pragma unroll
      for (int qd = 0; qd < 4; qd++) {
        half4_t hv, lv;
#pragma unroll
        for (int j = 0; j < 4; j++) {
          float tv = fmaxf(acc1[(qd << 2) + j], 0.f) * 0.00390625f;
          f16 h = (f16)tv; hv[j] = h; lv[j] = (f16)(tv - (float)h);
        }
        int c = (((w << 5) + (qd << 3) + (koct << 2)) + rot0) & 127;
        *(half4_t*)(Hh + (col << 7) + c) = hv;
        *(half4_t*)(Hl + (col << 7) + c) = lv;
      }
      __syncthreads();                       // H(hf0) visible to all waves

      // GEMM2(hf0): reads H(hf0)
      __builtin_amdgcn_s_setprio(1);
#pragma unroll
      for (int kc = 0; kc < 8; kc++) {
        int poff = (((kc << 4) + (koct << 3)) + rot0) & 127;
        half8_t bh0 = *(const half8_t*)(Hr0 + poff);
        half8_t bl0 = *(const half8_t*)(Hr0 + HLO + poff);
        acc2 = mfma_f16(a2hv[kc], bh0, acc2);
        acc2 = mfma_f16(a2lv[kc], bh0, acc2);
        acc2 = mfma_f16(a2hv[kc], bl0, acc2);
      }
      __builtin_amdgcn_s_setprio(0);
      // NO barrier here: the hazard (H overwrite) is at storeH(hf1) below.

      // ================= hf 1 =================
      {
        const f16* a1p = w1h + (size_t)(128 + (w << 5) + col) * 128 + (koct << 3);
#pragma unroll
        for (int kc = 0; kc < 8; kc++) {
          a1hv[kc] = *(const half8_t*)(a1p + (kc << 4));
          a1lv[kc] = *(const half8_t*)(a1p + NW1 + (kc << 4));
        }
      }
#pragma unroll
      for (int i = 0; i < 16; i++) acc1[i] = 0.f;
      __builtin_amdgcn_s_setprio(1);
#pragma unroll
      for (int kc = 0; kc < 8; kc++) {
        int poff = (((kc << 4) + (koct << 3)) + rot0) & 127;
        half8_t bh0 = *(const half8_t*)(Zr0 + poff);
        half8_t bl0 = *(const half8_t*)(Zr0 + HLO + poff);
        acc1 = mfma_f16(a1hv[kc], bh0, acc1);
        acc1 = mfma_f16(a1lv[kc], bh0, acc1);
        acc1 = mfma_f16(a1hv[kc], bl0, acc1);
      }
      __builtin_amdgcn_s_setprio(0);

      // a2(hf1) loads: hide under the two barriers + epilogue below
      {
        const f16* a2q = w2h + (size_t)((w << 5) + col) * 256 + 128 + (koct << 3);
#pragma unroll
        for (int kc = 0; kc < 8; kc++) {
          a2hv[kc] = *(const half8_t*)(a2q + (kc << 4));
          a2lv[kc] = *(const half8_t*)(a2q + NW1 + (kc << 4));
        }
      }
      __syncthreads();                       // all waves done READING H(hf0)

      // epilogue1: store H(hf1)
#pragma unroll
      for (int qd = 0; qd < 4; qd++) {
        half4_t hv, lv;
#pragma unroll
        for (int j = 0; j < 4; j++) {
          float tv = fmaxf(acc1[(qd << 2) + j], 0.f) * 0.00390625f;
          f16 h = (f16)tv; hv[j] = h; lv[j] = (f16)(tv - (float)h);
        }
        int c = (((w << 5) + (qd << 3) + (koct << 2)) + rot0) & 127;
        *(half4_t*)(Hh + (col << 7) + c) = hv;
        *(half4_t*)(Hl + (col << 7) + c) = lv;
      }
      __syncthreads();                       // H(hf1) visible

      // GEMM2(hf1)
      __builtin_amdgcn_s_setprio(1);
#pragma unroll
      for (int kc = 0; kc < 8; kc++) {
        int poff = (((kc << 4) + (koct << 3)) + rot0) & 127;
        half8_t bh0 = *(const half8_t*)(Hr0 + poff);
        half8_t bl0 = *(const half8_t*)(Hr0 + HLO + poff);
        acc2 = mfma_f16(a2hv[kc], bh0, acc2);
        acc2 = mfma_f16(a2lv[kc], bh0, acc2);
        acc2 = mfma_f16(a2hv[kc], bl0, acc2);
      }
      __builtin_amdgcn_s_setprio(0);

      // epilogue2: Z[m=col][32w + d_local] += acc2 * 2^-8 (scaled units)
      {
        f16* zhr = Zh + (col << 7);
        f16* zlr = Zl + (col << 7);
#pragma unroll
        for (int qd = 0; qd < 4; qd++) {
          int c = (((w << 5) + (qd << 3) + (koct << 2)) + rot0) & 127;
          half4_t zh = *(half4_t*)(zhr + c);
          half4_t zl = *(half4_t*)(zlr + c);
#pragma unroll
          for (int j = 0; j < 4; j++) {
            float zs = (float)zh[j] + (float)zl[j];
            zs += acc2[(qd << 2) + j] * 0.00390625f;
            f16 h = (f16)zs; zh[j] = h; zl[j] = (f16)(zs - (float)h);
          }
          *(half4_t*)(zhr + c) = zh;
          *(half4_t*)(zlr + c) = zl;
        }
      }
      __syncthreads();                       // Z visible (next layer / dist)
    }

    // ---- dist = ||rb - z||^2 over 32 rows (4 threads/row, 32 d each) ----
    if (tx < 128) {
      int row = tx >> 2, seg = tx & 3;
      int rotr = (row & 15) << 3;
      const f16* zhr = Zh + (row << 7);
      const f16* zlr = Zl + (row << 7);
      const float* rb = ws + WS_RB + b * 128 + (seg << 5);
      float s = 0.f;
#pragma unroll
      for (int o = 0; o < 4; o++) {
        int c = (((seg << 5) + (o << 3)) + rotr) & 127;
        half8_t zh = *(const half8_t*)(zhr + c);
        half8_t zl = *(const half8_t*)(zlr + c);
        float4 r0 = *(const float4*)(rb + (o << 3));
        float4 r1 = *(const float4*)(rb + (o << 3) + 4);
        float rr[8] = {r0.x, r0.y, r0.z, r0.w, r1.x, r1.y, r1.z, r1.w};
#pragma unroll
        for (int j = 0; j < 8; j++) {
          float z = ((float)zh[j] + (float)zl[j]) * 0.00390625f;
          float dlt = rr[j] - z;
          s += dlt * dlt;
        }
      }
      s += __shfl_xor(s, 1);   // all 4 lanes of a row end bit-identical
      s += __shfl_xor(s, 2);
      if (seg == 0) pd[row] = s;
    }
    __syncthreads();
    if (tx < 32) {
      float v = pd[tx]; int idx = tx;
#pragma unroll
      for (int off = 16; off; off >>= 1) {
        float v2 = __shfl_xor(v, off);
        int   i2 = __shfl_xor(idx, off);
        if (v2 < v || (v2 == v && i2 < idx)) { v = v2; idx = i2; }
      }
      if (tx == 0) {
        int better = (v < bestd) ? 1 : 0;    // strict <: ties -> lower k (st order)
        if (better) { bestd = v; besti = kb + idx; rwin[0] = idx; }
        rwin[1] = better;
      }
    }
    __syncthreads();
    if (rwin[1] && tx < 32) {
      int rw = rwin[0];
      int c = ((tx << 2) + ((rw & 15) << 3)) & 127;
      half4_t zh = *(const half4_t*)(Zh + (rw << 7) + c);
      half4_t zl = *(const half4_t*)(Zl + (rw << 7) + c);
      float4 z;
      z.x = ((float)zh[0] + (float)zl[0]) * 0.00390625f;
      z.y = ((float)zh[1] + (float)zl[1]) * 0.00390625f;
      z.z = ((float)zh[2] + (float)zl[2]) * 0.00390625f;
      z.w = ((float)zh[3] + (float)zl[3]) * 0.00390625f;
      *(float4*)(ws + WS_BESTZ + (((b << 2) + t) << 7) + (tx << 2)) = z;
    }
    __syncthreads();   // BESTZ read of Z done before next subtile's init overwrites
  }

  if (tx == 0) {
    ws[WS_BESTD + (b << 2) + t] = bestd;
    ((int*)ws)[WS_BESTI + (b << 2) + t] = besti;
  }
}

// ---------------- per-step update: pick tile winner, advance xhat ----------------
__global__ __launch_bounds__(128) void k_update(const float* __restrict__ x,
    float* __restrict__ ws, float* __restrict__ out, int m, int last)
{
  __shared__ int tsel;
  int tx = threadIdx.x, b = blockIdx.x;
  if (tx == 0) {
    float bv = ws[WS_BESTD + (b << 2)]; int bt = 0;
    for (int q = 1; q < 4; q++) {
      float v = ws[WS_BESTD + (b << 2) + q];
      if (v < bv) { bv = v; bt = q; }     // strict <: ties -> lowest k (tile order)
    }
    tsel = bt;
    int k = ((const int*)ws)[WS_BESTI + (b << 2) + bt];
    out[OUT_CODES + b * 8 + (m + 1)] = (float)k;
  }
  __syncthreads();
  int bt = tsel;
  float z  = ws[WS_BESTZ + (((b << 2) + bt) << 7) + tx];
  float xh = ws[WS_XHAT + b * 128 + tx] + z;
  ws[WS_XHAT + b * 128 + tx] = xh;
  ws[WS_RB   + b * 128 + tx] = x[b * 128 + tx] - xh;
  out[OUT_SIDE + (m + 1) * 131072 + b * 128 + tx] = xh;
  if (last) out[b * 128 + tx] = xh;       // final xhat == side[7]
}

extern "C" void kernel_launch(void* const* d_in, const int* in_sizes, int n_in,
                              void* d_out, int out_size, void* d_ws, size_t ws_size,
                              hipStream_t stream)
{
  const float* x   = (const float*)d_in[0];
  const float* cb0 = (const float*)d_in[1];
  const float* cbs = (const float*)d_in[2];
  const float* Wc  = (const float*)d_in[3];
  const float* bc  = (const float*)d_in[4];
  const float* W1  = (const float*)d_in[5];
  const float* W2  = (const float*)d_in[6];
  float* out = (float*)d_out;
  float* ws  = (float*)d_ws;
  f16* wsh = (f16*)(ws + WS_WSPLIT);

  k_wsplit<<<896, 256, 0, stream>>>(W1, W2, wsh);
  k_step0<<<1024, 256, 0, stream>>>(x, cb0, ws, out);
  for (int m = 0; m < 7; m++) {
    k_prep<<<1280, 128, 0, stream>>>(cbs + m * 256 * 128, Wc + m * 128 * 256,
                                     bc + m * 128, ws);
    k_step<<<4096, 256, 0, stream>>>(wsh, ws, m);
    k_update<<<1024, 128, 0, stream>>>(x, ws, out, m, (m == 6) ? 1 : 0);
  }
}

// Round 4
// 3090.862 us; speedup vs baseline: 1.2175x; 1.2175x over previous
//
#include <hip/hip_runtime.h>

// QINCo round 14: occupancy attack, register-safe this time.
//  - LDS 64KB -> 48KB: full 64-row Z tile (32KB) + QUARTER H buffer (64 h,
//    16KB). GEMM1/GEMM2 run as 4 quarter-phases per layer (was 2 halves).
//    3 blocks/CU by LDS (was 2) -> 3 waves/SIMD.
//  - __launch_bounds__(256, 3): 170-reg budget, fits the ~140-reg live set.
//    (R11/R13 lesson: a 4-wave/SIMD budget (128) spills catastrophically.)
//  - G1 per quarter: 1 chain x 24 MFMA/wave (tile [32h][32m]).
//    G2 per quarter: 2 chains x 12 MFMA/wave; acc2 carried across quarters.
//    Same per-acc MFMA order (hh, lh, hl) and hi/lo numerics as R12.
//  - H rotation is mod-64: phys = (h + 8*(m&7)) & 63 (aggregate conflict-free).
//  - Z layout / dist / BESTZ / ws layout unchanged from R12.
// Shapes: D=128, M=8, K=256, L=2, H=256, BS=1024.
// Out layout (floats): xhat[1024*128] | codes[1024*8] | side[8][1024*128]

typedef _Float16 f16;
typedef f16 half4_t __attribute__((ext_vector_type(4)));
typedef f16 half8_t __attribute__((ext_vector_type(8)));
typedef float f32x16 __attribute__((ext_vector_type(16)));

#define OUT_CODES 131072
#define OUT_SIDE  139264

// ws float offsets (unchanged)
#define WS_XHAT  0          // [1024][128]
#define WS_RB    131072     // [1024][128]  r = x - xhat
#define WS_Y     262144     // [1024][128]  y = xhat @ Wx^T
#define WS_ZC    393216     // [256][128]   zc = cb + cb@Wz^T + bc
#define WS_BESTD 425984     // [1024][4]
#define WS_BESTI 430080     // [1024][4] (int)
#define WS_BESTZ 434176     // [1024][4][128]
#define WS_WSPLIT 960000    // f16 region: W1H|W1L|W2H|W2L, NW1 halfs each
#define NW1 458752          // 7*2*256*128

#define ZLO 8192            // Zh -> Zl offset (halfs)
#define HLOQ 4096           // Hh -> Hl offset (halfs), quarter buffer [64][64]

__device__ __forceinline__ f32x16 mfma_f16(half8_t a, half8_t b, f32x16 c) {
  return __builtin_amdgcn_mfma_f32_32x32x16_f16(a, b, c, 0, 0, 0);
}

// ---------------- weight pre-split: fp32 -> scaled (x256) fp16 hi/lo ----------------
__global__ __launch_bounds__(256) void k_wsplit(const float* __restrict__ W1,
    const float* __restrict__ W2, f16* __restrict__ wsh)
{
  int i = (blockIdx.x * 256 + threadIdx.x) * 4;      // [0, 2*NW1)
  const float* src;
  f16* hi;
  if (i < NW1) { src = W1 + i; hi = wsh + i; }
  else         { src = W2 + (i - NW1); hi = wsh + 2 * NW1 + (i - NW1); }
  f16* lo = hi + NW1;
  float4 v = *(const float4*)src;
  half4_t h, l;
  float s;
  s = v.x * 256.f; h[0] = (f16)s; l[0] = (f16)(s - (float)h[0]);
  s = v.y * 256.f; h[1] = (f16)s; l[1] = (f16)(s - (float)h[1]);
  s = v.z * 256.f; h[2] = (f16)s; l[2] = (f16)(s - (float)h[2]);
  s = v.w * 256.f; h[3] = (f16)s; l[3] = (f16)(s - (float)h[3]);
  *(half4_t*)hi = h;
  *(half4_t*)lo = l;
}

// ---------------- step 0: nearest codebook0 row ----------------
__global__ __launch_bounds__(256) void k_step0(const float* __restrict__ x,
    const float* __restrict__ cb0, float* __restrict__ ws, float* __restrict__ out)
{
  __shared__ float xs[128];
  __shared__ float redv[4];
  __shared__ int   redi[4];
  __shared__ int   kwin;
  int tx = threadIdx.x, b = blockIdx.x;
  if (tx < 128) xs[tx] = x[b * 128 + tx];
  __syncthreads();
  const float* c = cb0 + tx * 128;   // k = tx
  float s = 0.f;
  for (int d = 0; d < 128; d += 4) {
    float4 cv = *(const float4*)(c + d);
    float4 xv = *(const float4*)(xs + d);
    float a0 = xv.x - cv.x, a1 = xv.y - cv.y, a2 = xv.z - cv.z, a3 = xv.w - cv.w;
    s += a0 * a0 + a1 * a1 + a2 * a2 + a3 * a3;
  }
  float v = s; int idx = tx;
  for (int off = 32; off; off >>= 1) {
    float v2 = __shfl_xor(v, off);
    int   i2 = __shfl_xor(idx, off);
    if (v2 < v || (v2 == v && i2 < idx)) { v = v2; idx = i2; }
  }
  if ((tx & 63) == 0) { redv[tx >> 6] = v; redi[tx >> 6] = idx; }
  __syncthreads();
  if (tx == 0) {
    float bv = redv[0]; int bi = redi[0];
    for (int w = 1; w < 4; w++)
      if (redv[w] < bv || (redv[w] == bv && redi[w] < bi)) { bv = redv[w]; bi = redi[w]; }
    kwin = bi;
    out[OUT_CODES + b * 8] = (float)bi;
  }
  __syncthreads();
  int k = kwin;
  if (tx < 128) {
    float xh = cb0[k * 128 + tx];
    ws[WS_XHAT + b * 128 + tx] = xh;
    ws[WS_RB   + b * 128 + tx] = xs[tx] - xh;
    out[OUT_SIDE + b * 128 + tx] = xh;   // side[0]
  }
}

// ---------------- per-step prep: zc and y (fp32) ----------------
__global__ __launch_bounds__(128) void k_prep(const float* __restrict__ cb,
    const float* __restrict__ Wc, const float* __restrict__ bcm, float* __restrict__ ws)
{
  __shared__ float row[128];
  int tx = threadIdx.x, blk = blockIdx.x;
  if (blk < 256) {          // zc[k][i] = cb[k][i] + sum_d cb[k][d]*Wc[i][d] + bc[i]
    row[tx] = cb[blk * 128 + tx];
    __syncthreads();
    const float* wrow = Wc + tx * 256;
    float s = 0.f;
    for (int d = 0; d < 128; d += 4) {
      float4 wv = *(const float4*)(wrow + d);
      float4 zv = *(const float4*)(row + d);
      s += wv.x * zv.x + wv.y * zv.y + wv.z * zv.z + wv.w * zv.w;
    }
    ws[WS_ZC + blk * 128 + tx] = row[tx] + s + bcm[tx];
  } else {                  // y[b][i] = sum_d xhat[b][d]*Wc[i][128+d]
    int b = blk - 256;
    row[tx] = ws[WS_XHAT + b * 128 + tx];
    __syncthreads();
    const float* wrow = Wc + tx * 256 + 128;
    float s = 0.f;
    for (int d = 0; d < 128; d += 4) {
      float4 wv = *(const float4*)(wrow + d);
      float4 zv = *(const float4*)(row + d);
      s += wv.x * zv.x + wv.y * zv.y + wv.z * zv.z + wv.w * zv.w;
    }
    ws[WS_Y + b * 128 + tx] = s;
  }
}

// ---------------- main step kernel ----------------
// 256 threads = 4 waves. lane: col = lane&31, koct = lane>>5.
// Z rows 128 halfs, rotation (d + 8*(m&15)) & 127 (unchanged).
// H quarter buffer [64 m][64 h_local], rotation (h + 8*(m&7)) & 63.
// Per layer: 4 quarters q: { loadA1(q done prev) | G1(q) | loadA2(q),A1(q+1) |
//   storeH(q) | bar | G2(q) | bar(if q<3) } then epi2 | bar.
// C/D layout: col(lane&31) = N index; row = (reg&3)+8*(reg>>2)+4*koct.
__global__ __launch_bounds__(256, 3) void k_step(const f16* __restrict__ wsh,
    float* __restrict__ ws, int sm)
{
  __shared__ __align__(16) f16 lds[24576];     // 48 KB exactly
  f16* Zh = lds;            // [64][128]
  f16* Zl = lds + ZLO;
  f16* Hh = lds + 2 * ZLO;  // [64][64]
  f16* Hl = Hh + HLOQ;
  int tx = threadIdx.x;
  int lane = tx & 63, w = tx >> 6;
  int col = lane & 31, koct = lane >> 5;
  int b = blockIdx.x >> 2, t = blockIdx.x & 3, k0 = t << 6;

  // ---- init Z = zc[k0+m] + y[b], split x256 into Zh/Zl (rotated store) ----
  {
    const float* zc = ws + WS_ZC + k0 * 128;
    const float* y  = ws + WS_Y + b * 128;
    for (int idx = tx; idx < 1024; idx += 256) {
      int m = idx & 63, d0 = (idx >> 6) << 3;
      float4 a  = *(const float4*)(zc + m * 128 + d0);
      float4 bb = *(const float4*)(zc + m * 128 + d0 + 4);
      float4 ya = *(const float4*)(y + d0);
      float4 yb = *(const float4*)(y + d0 + 4);
      float sv[8] = {a.x + ya.x, a.y + ya.y, a.z + ya.z, a.w + ya.w,
                     bb.x + yb.x, bb.y + yb.y, bb.z + yb.z, bb.w + yb.w};
      half8_t h8, l8;
#pragma unroll
      for (int j = 0; j < 8; j++) {
        float v = sv[j] * 256.f;
        f16 h = (f16)v; h8[j] = h; l8[j] = (f16)(v - (float)h);
      }
      int c0 = (d0 + ((m & 15) << 3)) & 127;
      *(half8_t*)(Zh + (m << 7) + c0) = h8;
      *(half8_t*)(Zl + (m << 7) + c0) = l8;
    }
  }
  __syncthreads();

  const int rot0 = (col & 15) << 3;        // Z rotation for rows col / col+32
  const int rotH = (col & 7) << 3;         // H rotation (mod-64 layout)
  // G1: this wave's single chain: m-tile (w&1), h-tile (w>>1)
  const int mrow1 = ((w & 1) << 5) + col;  // B row in Z for G1
  const f16* Zg1 = Zh + (mrow1 << 7);
  const int rotG1 = (col & 15) << 3;       // (mrow1 & 15) == (col & 15)
  // G2: 2 chains, B rows col and col+32 in H
  const f16* Hr0 = Hh + (col << 6);
  const f16* Hr1 = Hh + ((col + 32) << 6);

  float* pd = (float*)Hh;                  // dist scratch (H dead by then)
  int* rwin = (int*)Hh + 64;

  for (int l = 0; l < 2; l++) {
    const f16* w1h = wsh + (size_t)((sm * 2 + l) * 256) * 128;
    const f16* w2h = wsh + 2 * NW1 + (size_t)((sm * 2 + l) * 128) * 256;
    f32x16 acc2[2];
#pragma unroll
    for (int i = 0; i < 16; i++) { acc2[0][i] = 0.f; acc2[1][i] = 0.f; }

    // preload A1 for q=0: W1 row h = (w>>1)*32 + col, all 128 d
    half8_t a1hv[8], a1lv[8];
    {
      const f16* a1p = w1h + (size_t)(((w >> 1) << 5) + col) * 128 + (koct << 3);
#pragma unroll
      for (int kc = 0; kc < 8; kc++) {
        a1hv[kc] = *(const half8_t*)(a1p + (kc << 4));
        a1lv[kc] = *(const half8_t*)(a1p + NW1 + (kc << 4));
      }
    }

#pragma unroll
    for (int q = 0; q < 4; q++) {
      // ---- G1(q): acc1 = W1[h-tile] x Z[m-tile], 1 chain x 24 MFMA ----
      f32x16 acc1;
#pragma unroll
      for (int i = 0; i < 16; i++) acc1[i] = 0.f;
      __builtin_amdgcn_s_setprio(1);
#pragma unroll
      for (int kc = 0; kc < 8; kc++) {
        int poff = (((kc << 4) + (koct << 3)) + rotG1) & 127;
        half8_t bh = *(const half8_t*)(Zg1 + poff);
        half8_t bl = *(const half8_t*)(Zg1 + ZLO + poff);
        acc1 = mfma_f16(a1hv[kc], bh, acc1);
        acc1 = mfma_f16(a1lv[kc], bh, acc1);
        acc1 = mfma_f16(a1hv[kc], bl, acc1);
      }
      __builtin_amdgcn_s_setprio(0);

      // ---- issue A2(q); and A1(q+1) for next quarter (hide under store+bar) ----
      half8_t a2hv[4], a2lv[4];
      {
        const f16* a2p = w2h + (size_t)((w << 5) + col) * 256 + (q << 6) + (koct << 3);
#pragma unroll
        for (int kc = 0; kc < 4; kc++) {
          a2hv[kc] = *(const half8_t*)(a2p + (kc << 4));
          a2lv[kc] = *(const half8_t*)(a2p + NW1 + (kc << 4));
        }
      }
      if (q < 3) {
        const f16* a1p = w1h + (size_t)(((q + 1) << 6) + ((w >> 1) << 5) + col) * 128
                       + (koct << 3);
#pragma unroll
        for (int kc = 0; kc < 8; kc++) {
          a1hv[kc] = *(const half8_t*)(a1p + (kc << 4));
          a1lv[kc] = *(const half8_t*)(a1p + NW1 + (kc << 4));
        }
      }

      // ---- storeH(q): relu, rescale, split; m = (w&1)*32+col, h-tile (w>>1) ----
      {
        int m = ((w & 1) << 5) + col;
#pragma unroll
        for (int qd = 0; qd < 4; qd++) {
          half4_t hv, lv;
#pragma unroll
          for (int j = 0; j < 4; j++) {
            float tv = fmaxf(acc1[(qd << 2) + j], 0.f) * 0.00390625f;
            f16 h = (f16)tv; hv[j] = h; lv[j] = (f16)(tv - (float)h);
          }
          int hb = ((w >> 1) << 5) + (qd << 3) + (koct << 2);
          int c = (hb + rotH) & 63;        // (m&7)==(col&7) rotation
          *(half4_t*)(Hh + (m << 6) + c) = hv;
          *(half4_t*)(Hl + (m << 6) + c) = lv;
        }
      }
      __syncthreads();                     // H(q) visible to all waves

      // ---- G2(q): acc2 += W2[:, 64q..] x H(q), 2 chains x 12 MFMA ----
      __builtin_amdgcn_s_setprio(1);
#pragma unroll
      for (int kc = 0; kc < 4; kc++) {
        int poff = (((kc << 4) + (koct << 3)) + rotH) & 63;
        half8_t bh0 = *(const half8_t*)(Hr0 + poff);
        half8_t bl0 = *(const half8_t*)(Hr0 + HLOQ + poff);
        half8_t bh1 = *(const half8_t*)(Hr1 + poff);
        half8_t bl1 = *(const half8_t*)(Hr1 + HLOQ + poff);
        acc2[0] = mfma_f16(a2hv[kc], bh0, acc2[0]);
        acc2[1] = mfma_f16(a2hv[kc], bh1, acc2[1]);
        acc2[0] = mfma_f16(a2lv[kc], bh0, acc2[0]);
        acc2[1] = mfma_f16(a2lv[kc], bh1, acc2[1]);
        acc2[0] = mfma_f16(a2hv[kc], bl0, acc2[0]);
        acc2[1] = mfma_f16(a2hv[kc], bl1, acc2[1]);
      }
      __builtin_amdgcn_s_setprio(0);
      if (q < 3) __syncthreads();          // readers done before storeH(q+1)
    }

    // ---- epilogue2: Z[m][32w + d_local] += acc2 * 2^-8 (scaled units) ----
    // No barrier needed before this: all waves' last Z-reads (G1 q3) precede
    // the post-storeH(3) barrier; G2(3) reads H only. Per-wave Z-write columns
    // are disjoint (32w block).
#pragma unroll
    for (int mt = 0; mt < 2; mt++) {
      int m = (mt << 5) + col;
      f16* zhr = Zh + (m << 7);
      f16* zlr = Zl + (m << 7);
#pragma unroll
      for (int qd = 0; qd < 4; qd++) {
        int c = (((w << 5) + (qd << 3) + (koct << 2)) + rot0) & 127;
        half4_t zh = *(half4_t*)(zhr + c);
        half4_t zl = *(half4_t*)(zlr + c);
#pragma unroll
        for (int j = 0; j < 4; j++) {
          float zs = (float)zh[j] + (float)zl[j];
          zs += acc2[mt][(qd << 2) + j] * 0.00390625f;
          f16 h = (f16)zs; zh[j] = h; zl[j] = (f16)(zs - (float)h);
        }
        *(half4_t*)(zhr + c) = zh;
        *(half4_t*)(zlr + c) = zl;
      }
    }
    __syncthreads();                       // Z visible (next layer / dist)
  }

  // ---- dist = ||rb - z||^2 over 64 rows (4 threads/row, 32 d each) ----
  {
    int row = tx >> 2, seg = tx & 3;
    int rotr = (row & 15) << 3;
    const f16* zhr = Zh + (row << 7);
    const f16* zlr = Zl + (row << 7);
    const float* rb = ws + WS_RB + b * 128 + (seg << 5);
    float s = 0.f;
#pragma unroll
    for (int o = 0; o < 4; o++) {
      int c = (((seg << 5) + (o << 3)) + rotr) & 127;
      half8_t zh = *(const half8_t*)(zhr + c);
      half8_t zl = *(const half8_t*)(zlr + c);
      float4 r0 = *(const float4*)(rb + (o << 3));
      float4 r1 = *(const float4*)(rb + (o << 3) + 4);
      float rr[8] = {r0.x, r0.y, r0.z, r0.w, r1.x, r1.y, r1.z, r1.w};
#pragma unroll
      for (int j = 0; j < 8; j++) {
        float z = ((float)zh[j] + (float)zl[j]) * 0.00390625f;
        float dlt = rr[j] - z;
        s += dlt * dlt;
      }
    }
    s += __shfl_xor(s, 1);   // all 4 lanes of a row end bit-identical
    s += __shfl_xor(s, 2);
    if (seg == 0) pd[row] = s;
  }
  __syncthreads();
  if (tx < 64) {
    float v = pd[tx]; int idx = tx;
#pragma unroll
    for (int off = 32; off; off >>= 1) {
      float v2 = __shfl_xor(v, off);
      int   i2 = __shfl_xor(idx, off);
      if (v2 < v || (v2 == v && i2 < idx)) { v = v2; idx = i2; }
    }
    if (tx == 0) {
      ws[WS_BESTD + (b << 2) + t] = v;
      ((int*)ws)[WS_BESTI + (b << 2) + t] = k0 + idx;
      rwin[0] = idx;
    }
  }
  __syncthreads();
  if (tx < 32) {
    int rw = rwin[0];
    int c = ((tx << 2) + ((rw & 15) << 3)) & 127;
    half4_t zh = *(const half4_t*)(Zh + (rw << 7) + c);
    half4_t zl = *(const half4_t*)(Zl + (rw << 7) + c);
    float4 z;
    z.x = ((float)zh[0] + (float)zl[0]) * 0.00390625f;
    z.y = ((float)zh[1] + (float)zl[1]) * 0.00390625f;
    z.z = ((float)zh[2] + (float)zl[2]) * 0.00390625f;
    z.w = ((float)zh[3] + (float)zl[3]) * 0.00390625f;
    *(float4*)(ws + WS_BESTZ + (((b << 2) + t) << 7) + (tx << 2)) = z;
  }
}

// ---------------- per-step update: pick tile winner, advance xhat ----------------
__global__ __launch_bounds__(128) void k_update(const float* __restrict__ x,
    float* __restrict__ ws, float* __restrict__ out, int m, int last)
{
  __shared__ int tsel;
  int tx = threadIdx.x, b = blockIdx.x;
  if (tx == 0) {
    float bv = ws[WS_BESTD + (b << 2)]; int bt = 0;
    for (int q = 1; q < 4; q++) {
      float v = ws[WS_BESTD + (b << 2) + q];
      if (v < bv) { bv = v; bt = q; }     // strict <: ties -> lowest k (tile order)
    }
    tsel = bt;
    int k = ((const int*)ws)[WS_BESTI + (b << 2) + bt];
    out[OUT_CODES + b * 8 + (m + 1)] = (float)k;
  }
  __syncthreads();
  int bt = tsel;
  float z  = ws[WS_BESTZ + (((b << 2) + bt) << 7) + tx];
  float xh = ws[WS_XHAT + b * 128 + tx] + z;
  ws[WS_XHAT + b * 128 + tx] = xh;
  ws[WS_RB   + b * 128 + tx] = x[b * 128 + tx] - xh;
  out[OUT_SIDE + (m + 1) * 131072 + b * 128 + tx] = xh;
  if (last) out[b * 128 + tx] = xh;       // final xhat == side[7]
}

extern "C" void kernel_launch(void* const* d_in, const int* in_sizes, int n_in,
                              void* d_out, int out_size, void* d_ws, size_t ws_size,
                              hipStream_t stream)
{
  const float* x   = (const float*)d_in[0];
  const float* cb0 = (const float*)d_in[1];
  const float* cbs = (const float*)d_in[2];
  const float* Wc  = (const float*)d_in[3];
  const float* bc  = (const float*)d_in[4];
  const float* W1  = (const float*)d_in[5];
  const float* W2  = (const float*)d_in[6];
  float* out = (float*)d_out;
  float* ws  = (float*)d_ws;
  f16* wsh = (f16*)(ws + WS_WSPLIT);

  k_wsplit<<<896, 256, 0, stream>>>(W1, W2, wsh);
  k_step0<<<1024, 256, 0, stream>>>(x, cb0, ws, out);
  for (int m = 0; m < 7; m++) {
    k_prep<<<1280, 128, 0, stream>>>(cbs + m * 256 * 128, Wc + m * 128 * 256,
                                     bc + m * 128, ws);
    k_step<<<4096, 256, 0, stream>>>(wsh, ws, m);
    k_update<<<1024, 128, 0, stream>>>(x, ws, out, m, (m == 6) ? 1 : 0);
  }
}

// Round 5
// 2158.644 us; speedup vs baseline: 1.7433x; 1.4319x over previous
//
#include <hip/hip_runtime.h>

// QINCo round 15: R12 base (2 blocks/CU, 64KB LDS, no spill) + depth-1
// software pipeline of the B-operand LDS reads in all 4 GEMM loops:
// kc+1's 4 ds_read_b128 are issued BEFORE kc's 6 MFMAs (rotating named regs,
// fully unrolled -> all static indices). Gives each read a 192-cyc MFMA block
// to cover its ~120-cyc LDS latency, which 2 waves/SIMD of TLP cannot.
// Numerics bit-identical to R12 (same MFMA order per accumulator).
// R13/R14 lesson: live set needs the 2-waves/SIMD register budget; occupancy
// attacks spill. Stay at (256,2).
// Shapes: D=128, M=8, K=256, L=2, H=256, BS=1024.
// Out layout (floats): xhat[1024*128] | codes[1024*8] | side[8][1024*128]

typedef _Float16 f16;
typedef f16 half4_t __attribute__((ext_vector_type(4)));
typedef f16 half8_t __attribute__((ext_vector_type(8)));
typedef float f32x16 __attribute__((ext_vector_type(16)));

#define OUT_CODES 131072
#define OUT_SIDE  139264

// ws float offsets
#define WS_XHAT  0          // [1024][128]
#define WS_RB    131072     // [1024][128]  r = x - xhat
#define WS_Y     262144     // [1024][128]  y = xhat @ Wx^T
#define WS_ZC    393216     // [256][128]   zc = cb + cb@Wz^T + bc
#define WS_BESTD 425984     // [1024][4]
#define WS_BESTI 430080     // [1024][4] (int)
#define WS_BESTZ 434176     // [1024][4][128]
#define WS_WSPLIT 960000    // f16 region: W1H|W1L|W2H|W2L, NW1 halfs each
#define NW1 458752          // 7*2*256*128

#define HLO 8192            // hi->lo LDS offset (halfs), compile-time

__device__ __forceinline__ f32x16 mfma_f16(half8_t a, half8_t b, f32x16 c) {
  return __builtin_amdgcn_mfma_f32_32x32x16_f16(a, b, c, 0, 0, 0);
}

// ---------------- weight pre-split: fp32 -> scaled (x256) fp16 hi/lo ----------------
__global__ __launch_bounds__(256) void k_wsplit(const float* __restrict__ W1,
    const float* __restrict__ W2, f16* __restrict__ wsh)
{
  int i = (blockIdx.x * 256 + threadIdx.x) * 4;      // [0, 2*NW1)
  const float* src;
  f16* hi;
  if (i < NW1) { src = W1 + i; hi = wsh + i; }
  else         { src = W2 + (i - NW1); hi = wsh + 2 * NW1 + (i - NW1); }
  f16* lo = hi + NW1;
  float4 v = *(const float4*)src;
  half4_t h, l;
  float s;
  s = v.x * 256.f; h[0] = (f16)s; l[0] = (f16)(s - (float)h[0]);
  s = v.y * 256.f; h[1] = (f16)s; l[1] = (f16)(s - (float)h[1]);
  s = v.z * 256.f; h[2] = (f16)s; l[2] = (f16)(s - (float)h[2]);
  s = v.w * 256.f; h[3] = (f16)s; l[3] = (f16)(s - (float)h[3]);
  *(half4_t*)hi = h;
  *(half4_t*)lo = l;
}

// ---------------- step 0: nearest codebook0 row ----------------
__global__ __launch_bounds__(256) void k_step0(const float* __restrict__ x,
    const float* __restrict__ cb0, float* __restrict__ ws, float* __restrict__ out)
{
  __shared__ float xs[128];
  __shared__ float redv[4];
  __shared__ int   redi[4];
  __shared__ int   kwin;
  int tx = threadIdx.x, b = blockIdx.x;
  if (tx < 128) xs[tx] = x[b * 128 + tx];
  __syncthreads();
  const float* c = cb0 + tx * 128;   // k = tx
  float s = 0.f;
  for (int d = 0; d < 128; d += 4) {
    float4 cv = *(const float4*)(c + d);
    float4 xv = *(const float4*)(xs + d);
    float a0 = xv.x - cv.x, a1 = xv.y - cv.y, a2 = xv.z - cv.z, a3 = xv.w - cv.w;
    s += a0 * a0 + a1 * a1 + a2 * a2 + a3 * a3;
  }
  float v = s; int idx = tx;
  for (int off = 32; off; off >>= 1) {
    float v2 = __shfl_xor(v, off);
    int   i2 = __shfl_xor(idx, off);
    if (v2 < v || (v2 == v && i2 < idx)) { v = v2; idx = i2; }
  }
  if ((tx & 63) == 0) { redv[tx >> 6] = v; redi[tx >> 6] = idx; }
  __syncthreads();
  if (tx == 0) {
    float bv = redv[0]; int bi = redi[0];
    for (int w = 1; w < 4; w++)
      if (redv[w] < bv || (redv[w] == bv && redi[w] < bi)) { bv = redv[w]; bi = redi[w]; }
    kwin = bi;
    out[OUT_CODES + b * 8] = (float)bi;
  }
  __syncthreads();
  int k = kwin;
  if (tx < 128) {
    float xh = cb0[k * 128 + tx];
    ws[WS_XHAT + b * 128 + tx] = xh;
    ws[WS_RB   + b * 128 + tx] = xs[tx] - xh;
    out[OUT_SIDE + b * 128 + tx] = xh;   // side[0]
  }
}

// ---------------- per-step prep: zc and y (fp32) ----------------
__global__ __launch_bounds__(128) void k_prep(const float* __restrict__ cb,
    const float* __restrict__ Wc, const float* __restrict__ bcm, float* __restrict__ ws)
{
  __shared__ float row[128];
  int tx = threadIdx.x, blk = blockIdx.x;
  if (blk < 256) {          // zc[k][i] = cb[k][i] + sum_d cb[k][d]*Wc[i][d] + bc[i]
    row[tx] = cb[blk * 128 + tx];
    __syncthreads();
    const float* wrow = Wc + tx * 256;
    float s = 0.f;
    for (int d = 0; d < 128; d += 4) {
      float4 wv = *(const float4*)(wrow + d);
      float4 zv = *(const float4*)(row + d);
      s += wv.x * zv.x + wv.y * zv.y + wv.z * zv.z + wv.w * zv.w;
    }
    ws[WS_ZC + blk * 128 + tx] = row[tx] + s + bcm[tx];
  } else {                  // y[b][i] = sum_d xhat[b][d]*Wc[i][128+d]
    int b = blk - 256;
    row[tx] = ws[WS_XHAT + b * 128 + tx];
    __syncthreads();
    const float* wrow = Wc + tx * 256 + 128;
    float s = 0.f;
    for (int d = 0; d < 128; d += 4) {
      float4 wv = *(const float4*)(wrow + d);
      float4 zv = *(const float4*)(row + d);
      s += wv.x * zv.x + wv.y * zv.y + wv.z * zv.z + wv.w * zv.w;
    }
    ws[WS_Y + b * 128 + tx] = s;
  }
}

// ---------------- main step kernel ----------------
// 256 threads = 4 waves. lane: col = lane&31, koct = lane>>5.
// LDS rows 128 halfs; logical d of row m at phys (d + 8*(m&15)) & 127.
// Layer schedule (4 barriers), same as R12:
//   G1(hf0) | storeH0 | bar | G2(hf0) | loadA1(hf1) | G1(hf1) | bar |
//   storeH1 | bar | G2(hf1) | epi2 | bar
// All GEMM inner loops are depth-1 pipelined on the B reads.
// C/D layout: col(lane&31) = N index (m); row M = (reg&3)+8*(reg>>2)+4*koct.
__global__ __launch_bounds__(256, 2) void k_step(const f16* __restrict__ wsh,
    float* __restrict__ ws, int sm)
{
  __shared__ __align__(16) f16 lds[32768];     // 64 KB exactly
  f16* Zh = lds;            // [64][128]
  f16* Zl = lds + HLO;
  f16* Hh = lds + 2 * HLO;
  f16* Hl = lds + 3 * HLO;  // Hl - Hh == Zl - Zh == HLO by construction
  int tx = threadIdx.x;
  int lane = tx & 63, w = tx >> 6;
  int col = lane & 31, koct = lane >> 5;
  int b = blockIdx.x >> 2, t = blockIdx.x & 3, k0 = t << 6;

  // ---- init Z = zc[k0+m] + y[b], split x256 into Zh/Zl (rotated store) ----
  {
    const float* zc = ws + WS_ZC + k0 * 128;
    const float* y  = ws + WS_Y + b * 128;
    for (int idx = tx; idx < 1024; idx += 256) {
      int m = idx & 63, d0 = (idx >> 6) << 3;
      float4 a  = *(const float4*)(zc + m * 128 + d0);
      float4 bb = *(const float4*)(zc + m * 128 + d0 + 4);
      float4 ya = *(const float4*)(y + d0);
      float4 yb = *(const float4*)(y + d0 + 4);
      float sv[8] = {a.x + ya.x, a.y + ya.y, a.z + ya.z, a.w + ya.w,
                     bb.x + yb.x, bb.y + yb.y, bb.z + yb.z, bb.w + yb.w};
      half8_t h8, l8;
#pragma unroll
      for (int j = 0; j < 8; j++) {
        float v = sv[j] * 256.f;
        f16 h = (f16)v; h8[j] = h; l8[j] = (f16)(v - (float)h);
      }
      int c0 = (d0 + ((m & 15) << 3)) & 127;
      *(half8_t*)(Zh + (m << 7) + c0) = h8;
      *(half8_t*)(Zl + (m << 7) + c0) = l8;
    }
  }
  __syncthreads();

  const int rot0 = (col & 15) << 3;        // rotation for rows col and col+32
  const f16* Zr0 = Zh + (col << 7);
  const f16* Zr1 = Zh + ((col + 32) << 7);
  const f16* Hr0 = Hh + (col << 7);
  const f16* Hr1 = Hh + ((col + 32) << 7);

  // LDS byte offsets for the 8 kc sub-steps (shared by all 4 GEMMs; CSE'd)
  int poffs[8];
#pragma unroll
  for (int kc = 0; kc < 8; kc++)
    poffs[kc] = (((kc << 4) + (koct << 3)) + rot0) & 127;

  for (int l = 0; l < 2; l++) {
    const f16* w1h = wsh + (size_t)((sm * 2 + l) * 256) * 128;
    const f16* w2h = wsh + 2 * NW1 + (size_t)((sm * 2 + l) * 128) * 256;
    f32x16 acc2[2];
#pragma unroll
    for (int i = 0; i < 16; i++) { acc2[0][i] = 0.f; acc2[1][i] = 0.f; }

    // ================= hf 0 =================
    half8_t a1hv[8], a1lv[8];
    {
      const f16* a1p = w1h + (size_t)((w << 5) + col) * 128 + (koct << 3);
#pragma unroll
      for (int kc = 0; kc < 8; kc++) {
        a1hv[kc] = *(const half8_t*)(a1p + (kc << 4));
        a1lv[kc] = *(const half8_t*)(a1p + NW1 + (kc << 4));
      }
    }
    f32x16 acc1[2];
#pragma unroll
    for (int i = 0; i < 16; i++) { acc1[0][i] = 0.f; acc1[1][i] = 0.f; }

    // G1(hf0): depth-1 pipelined
    {
      half8_t bh0 = *(const half8_t*)(Zr0 + poffs[0]);
      half8_t bl0 = *(const half8_t*)(Zr0 + HLO + poffs[0]);
      half8_t bh1 = *(const half8_t*)(Zr1 + poffs[0]);
      half8_t bl1 = *(const half8_t*)(Zr1 + HLO + poffs[0]);
      __builtin_amdgcn_s_setprio(1);
#pragma unroll
      for (int kc = 0; kc < 8; kc++) {
        half8_t nh0, nl0, nh1, nl1;
        if (kc < 7) {
          nh0 = *(const half8_t*)(Zr0 + poffs[kc + 1]);
          nl0 = *(const half8_t*)(Zr0 + HLO + poffs[kc + 1]);
          nh1 = *(const half8_t*)(Zr1 + poffs[kc + 1]);
          nl1 = *(const half8_t*)(Zr1 + HLO + poffs[kc + 1]);
        }
        acc1[0] = mfma_f16(a1hv[kc], bh0, acc1[0]);
        acc1[1] = mfma_f16(a1hv[kc], bh1, acc1[1]);
        acc1[0] = mfma_f16(a1lv[kc], bh0, acc1[0]);
        acc1[1] = mfma_f16(a1lv[kc], bh1, acc1[1]);
        acc1[0] = mfma_f16(a1hv[kc], bl0, acc1[0]);
        acc1[1] = mfma_f16(a1hv[kc], bl1, acc1[1]);
        if (kc < 7) { bh0 = nh0; bl0 = nl0; bh1 = nh1; bl1 = nl1; }
      }
      __builtin_amdgcn_s_setprio(0);
    }

    // a2(hf0) loads: hide under epilogue + barrier
    half8_t a2hv[8], a2lv[8];
    {
      const f16* a2p = w2h + (size_t)((w << 5) + col) * 256 + (koct << 3);
#pragma unroll
      for (int kc = 0; kc < 8; kc++) {
        a2hv[kc] = *(const half8_t*)(a2p + (kc << 4));
        a2lv[kc] = *(const half8_t*)(a2p + NW1 + (kc << 4));
      }
    }

    // epilogue1: relu, rescale (x 2^-8), split, store H(hf0).
#pragma unroll
    for (int mt = 0; mt < 2; mt++) {
      int m = (mt << 5) + col;
#pragma unroll
      for (int qd = 0; qd < 4; qd++) {
        half4_t hv, lv;
#pragma unroll
        for (int j = 0; j < 4; j++) {
          float tv = fmaxf(acc1[mt][(qd << 2) + j], 0.f) * 0.00390625f;
          f16 h = (f16)tv; hv[j] = h; lv[j] = (f16)(tv - (float)h);
        }
        int c = (((w << 5) + (qd << 3) + (koct << 2)) + rot0) & 127;
        *(half4_t*)(Hh + (m << 7) + c) = hv;
        *(half4_t*)(Hl + (m << 7) + c) = lv;
      }
    }
    __syncthreads();                       // H(hf0) visible to all waves

    // G2(hf0): depth-1 pipelined, reads H(hf0)
    {
      half8_t bh0 = *(const half8_t*)(Hr0 + poffs[0]);
      half8_t bl0 = *(const half8_t*)(Hr0 + HLO + poffs[0]);
      half8_t bh1 = *(const half8_t*)(Hr1 + poffs[0]);
      half8_t bl1 = *(const half8_t*)(Hr1 + HLO + poffs[0]);
      __builtin_amdgcn_s_setprio(1);
#pragma unroll
      for (int kc = 0; kc < 8; kc++) {
        half8_t nh0, nl0, nh1, nl1;
        if (kc < 7) {
          nh0 = *(const half8_t*)(Hr0 + poffs[kc + 1]);
          nl0 = *(const half8_t*)(Hr0 + HLO + poffs[kc + 1]);
          nh1 = *(const half8_t*)(Hr1 + poffs[kc + 1]);
          nl1 = *(const half8_t*)(Hr1 + HLO + poffs[kc + 1]);
        }
        acc2[0] = mfma_f16(a2hv[kc], bh0, acc2[0]);
        acc2[1] = mfma_f16(a2hv[kc], bh1, acc2[1]);
        acc2[0] = mfma_f16(a2lv[kc], bh0, acc2[0]);
        acc2[1] = mfma_f16(a2lv[kc], bh1, acc2[1]);
        acc2[0] = mfma_f16(a2hv[kc], bl0, acc2[0]);
        acc2[1] = mfma_f16(a2hv[kc], bl1, acc2[1]);
        if (kc < 7) { bh0 = nh0; bl0 = nl0; bh1 = nh1; bl1 = nl1; }
      }
      __builtin_amdgcn_s_setprio(0);
    }
    // NO barrier here: the hazard (H overwrite) is at storeH(hf1) below.

    // ================= hf 1 =================
    {
      const f16* a1p = w1h + (size_t)(128 + (w << 5) + col) * 128 + (koct << 3);
#pragma unroll
      for (int kc = 0; kc < 8; kc++) {
        a1hv[kc] = *(const half8_t*)(a1p + (kc << 4));
        a1lv[kc] = *(const half8_t*)(a1p + NW1 + (kc << 4));
      }
    }
#pragma unroll
    for (int i = 0; i < 16; i++) { acc1[0][i] = 0.f; acc1[1][i] = 0.f; }

    // G1(hf1): depth-1 pipelined
    {
      half8_t bh0 = *(const half8_t*)(Zr0 + poffs[0]);
      half8_t bl0 = *(const half8_t*)(Zr0 + HLO + poffs[0]);
      half8_t bh1 = *(const half8_t*)(Zr1 + poffs[0]);
      half8_t bl1 = *(const half8_t*)(Zr1 + HLO + poffs[0]);
      __builtin_amdgcn_s_setprio(1);
#pragma unroll
      for (int kc = 0; kc < 8; kc++) {
        half8_t nh0, nl0, nh1, nl1;
        if (kc < 7) {
          nh0 = *(const half8_t*)(Zr0 + poffs[kc + 1]);
          nl0 = *(const half8_t*)(Zr0 + HLO + poffs[kc + 1]);
          nh1 = *(const half8_t*)(Zr1 + poffs[kc + 1]);
          nl1 = *(const half8_t*)(Zr1 + HLO + poffs[kc + 1]);
        }
        acc1[0] = mfma_f16(a1hv[kc], bh0, acc1[0]);
        acc1[1] = mfma_f16(a1hv[kc], bh1, acc1[1]);
        acc1[0] = mfma_f16(a1lv[kc], bh0, acc1[0]);
        acc1[1] = mfma_f16(a1lv[kc], bh1, acc1[1]);
        acc1[0] = mfma_f16(a1hv[kc], bl0, acc1[0]);
        acc1[1] = mfma_f16(a1hv[kc], bl1, acc1[1]);
        if (kc < 7) { bh0 = nh0; bl0 = nl0; bh1 = nh1; bl1 = nl1; }
      }
      __builtin_amdgcn_s_setprio(0);
    }

    // a2(hf1) loads: hide under the two barriers + epilogue below
    {
      const f16* a2q = w2h + (size_t)((w << 5) + col) * 256 + 128 + (koct << 3);
#pragma unroll
      for (int kc = 0; kc < 8; kc++) {
        a2hv[kc] = *(const half8_t*)(a2q + (kc << 4));
        a2lv[kc] = *(const half8_t*)(a2q + NW1 + (kc << 4));
      }
    }
    __syncthreads();                       // all waves done READING H(hf0)

    // epilogue1: store H(hf1)
#pragma unroll
    for (int mt = 0; mt < 2; mt++) {
      int m = (mt << 5) + col;
#pragma unroll
      for (int qd = 0; qd < 4; qd++) {
        half4_t hv, lv;
#pragma unroll
        for (int j = 0; j < 4; j++) {
          float tv = fmaxf(acc1[mt][(qd << 2) + j], 0.f) * 0.00390625f;
          f16 h = (f16)tv; hv[j] = h; lv[j] = (f16)(tv - (float)h);
        }
        int c = (((w << 5) + (qd << 3) + (koct << 2)) + rot0) & 127;
        *(half4_t*)(Hh + (m << 7) + c) = hv;
        *(half4_t*)(Hl + (m << 7) + c) = lv;
      }
    }
    __syncthreads();                       // H(hf1) visible

    // G2(hf1): depth-1 pipelined
    {
      half8_t bh0 = *(const half8_t*)(Hr0 + poffs[0]);
      half8_t bl0 = *(const half8_t*)(Hr0 + HLO + poffs[0]);
      half8_t bh1 = *(const half8_t*)(Hr1 + poffs[0]);
      half8_t bl1 = *(const half8_t*)(Hr1 + HLO + poffs[0]);
      __builtin_amdgcn_s_setprio(1);
#pragma unroll
      for (int kc = 0; kc < 8; kc++) {
        half8_t nh0, nl0, nh1, nl1;
        if (kc < 7) {
          nh0 = *(const half8_t*)(Hr0 + poffs[kc + 1]);
          nl0 = *(const half8_t*)(Hr0 + HLO + poffs[kc + 1]);
          nh1 = *(const half8_t*)(Hr1 + poffs[kc + 1]);
          nl1 = *(const half8_t*)(Hr1 + HLO + poffs[kc + 1]);
        }
        acc2[0] = mfma_f16(a2hv[kc], bh0, acc2[0]);
        acc2[1] = mfma_f16(a2hv[kc], bh1, acc2[1]);
        acc2[0] = mfma_f16(a2lv[kc], bh0, acc2[0]);
        acc2[1] = mfma_f16(a2lv[kc], bh1, acc2[1]);
        acc2[0] = mfma_f16(a2hv[kc], bl0, acc2[0]);
        acc2[1] = mfma_f16(a2hv[kc], bl1, acc2[1]);
        if (kc < 7) { bh0 = nh0; bl0 = nl0; bh1 = nh1; bl1 = nl1; }
      }
      __builtin_amdgcn_s_setprio(0);
    }

    // epilogue2: Z[m][32w + d_local] += acc2 * 2^-8 (scaled units).
#pragma unroll
    for (int mt = 0; mt < 2; mt++) {
      int m = (mt << 5) + col;
      f16* zhr = Zh + (m << 7);
      f16* zlr = Zl + (m << 7);
#pragma unroll
      for (int qd = 0; qd < 4; qd++) {
        int c = (((w << 5) + (qd << 3) + (koct << 2)) + rot0) & 127;
        half4_t zh = *(half4_t*)(zhr + c);
        half4_t zl = *(half4_t*)(zlr + c);
#pragma unroll
        for (int j = 0; j < 4; j++) {
          float zs = (float)zh[j] + (float)zl[j];
          zs += acc2[mt][(qd << 2) + j] * 0.00390625f;
          f16 h = (f16)zs; zh[j] = h; zl[j] = (f16)(zs - (float)h);
        }
        *(half4_t*)(zhr + c) = zh;
        *(half4_t*)(zlr + c) = zl;
      }
    }
    __syncthreads();                       // Z visible (next layer / dist)
  }

  // ---- dist = ||rb - z||^2 over 64 rows (4 threads/row, 32 d each) ----
  float* pd = (float*)Hh;
  int* rwin = (int*)Hh + 64;
  {
    int row = tx >> 2, seg = tx & 3;
    int rotr = (row & 15) << 3;
    const f16* zhr = Zh + (row << 7);
    const f16* zlr = Zl + (row << 7);
    const float* rb = ws + WS_RB + b * 128 + (seg << 5);
    float s = 0.f;
#pragma unroll
    for (int o = 0; o < 4; o++) {
      int c = (((seg << 5) + (o << 3)) + rotr) & 127;
      half8_t zh = *(const half8_t*)(zhr + c);
      half8_t zl = *(const half8_t*)(zlr + c);
      float4 r0 = *(const float4*)(rb + (o << 3));
      float4 r1 = *(const float4*)(rb + (o << 3) + 4);
      float rr[8] = {r0.x, r0.y, r0.z, r0.w, r1.x, r1.y, r1.z, r1.w};
#pragma unroll
      for (int j = 0; j < 8; j++) {
        float z = ((float)zh[j] + (float)zl[j]) * 0.00390625f;
        float dlt = rr[j] - z;
        s += dlt * dlt;
      }
    }
    s += __shfl_xor(s, 1);   // all 4 lanes of a row end bit-identical
    s += __shfl_xor(s, 2);
    if (seg == 0) pd[row] = s;
  }
  __syncthreads();
  if (tx < 64) {
    float v = pd[tx]; int idx = tx;
#pragma unroll
    for (int off = 32; off; off >>= 1) {
      float v2 = __shfl_xor(v, off);
      int   i2 = __shfl_xor(idx, off);
      if (v2 < v || (v2 == v && i2 < idx)) { v = v2; idx = i2; }
    }
    if (tx == 0) {
      ws[WS_BESTD + (b << 2) + t] = v;
      ((int*)ws)[WS_BESTI + (b << 2) + t] = k0 + idx;
      rwin[0] = idx;
    }
  }
  __syncthreads();
  if (tx < 32) {
    int rw = rwin[0];
    int c = ((tx << 2) + ((rw & 15) << 3)) & 127;
    half4_t zh = *(const half4_t*)(Zh + (rw << 7) + c);
    half4_t zl = *(const half4_t*)(Zl + (rw << 7) + c);
    float4 z;
    z.x = ((float)zh[0] + (float)zl[0]) * 0.00390625f;
    z.y = ((float)zh[1] + (float)zl[1]) * 0.00390625f;
    z.z = ((float)zh[2] + (float)zl[2]) * 0.00390625f;
    z.w = ((float)zh[3] + (float)zl[3]) * 0.00390625f;
    *(float4*)(ws + WS_BESTZ + (((b << 2) + t) << 7) + (tx << 2)) = z;
  }
}

// ---------------- per-step update: pick tile winner, advance xhat ----------------
__global__ __launch_bounds__(128) void k_update(const float* __restrict__ x,
    float* __restrict__ ws, float* __restrict__ out, int m, int last)
{
  __shared__ int tsel;
  int tx = threadIdx.x, b = blockIdx.x;
  if (tx == 0) {
    float bv = ws[WS_BESTD + (b << 2)]; int bt = 0;
    for (int q = 1; q < 4; q++) {
      float v = ws[WS_BESTD + (b << 2) + q];
      if (v < bv) { bv = v; bt = q; }     // strict <: ties -> lowest k (tile order)
    }
    tsel = bt;
    int k = ((const int*)ws)[WS_BESTI + (b << 2) + bt];
    out[OUT_CODES + b * 8 + (m + 1)] = (float)k;
  }
  __syncthreads();
  int bt = tsel;
  float z  = ws[WS_BESTZ + (((b << 2) + bt) << 7) + tx];
  float xh = ws[WS_XHAT + b * 128 + tx] + z;
  ws[WS_XHAT + b * 128 + tx] = xh;
  ws[WS_RB   + b * 128 + tx] = x[b * 128 + tx] - xh;
  out[OUT_SIDE + (m + 1) * 131072 + b * 128 + tx] = xh;
  if (last) out[b * 128 + tx] = xh;       // final xhat == side[7]
}

extern "C" void kernel_launch(void* const* d_in, const int* in_sizes, int n_in,
                              void* d_out, int out_size, void* d_ws, size_t ws_size,
                              hipStream_t stream)
{
  const float* x   = (const float*)d_in[0];
  const float* cb0 = (const float*)d_in[1];
  const float* cbs = (const float*)d_in[2];
  const float* Wc  = (const float*)d_in[3];
  const float* bc  = (const float*)d_in[4];
  const float* W1  = (const float*)d_in[5];
  const float* W2  = (const float*)d_in[6];
  float* out = (float*)d_out;
  float* ws  = (float*)d_ws;
  f16* wsh = (f16*)(ws + WS_WSPLIT);

  k_wsplit<<<896, 256, 0, stream>>>(W1, W2, wsh);
  k_step0<<<1024, 256, 0, stream>>>(x, cb0, ws, out);
  for (int m = 0; m < 7; m++) {
    k_prep<<<1280, 128, 0, stream>>>(cbs + m * 256 * 128, Wc + m * 128 * 256,
                                     bc + m * 128, ws);
    k_step<<<4096, 256, 0, stream>>>(wsh, ws, m);
    k_update<<<1024, 128, 0, stream>>>(x, ws, out, m, (m == 6) ? 1 : 0);
  }
}